// Round 4
// baseline (113.304 us; speedup 1.0000x reference)
//
#include <hip/hip_runtime.h>
#include <hip/hip_bf16.h>

#define NN 384
#define HH 768
#define L2E 1.4426950408889634f
#define TWO_L2E 2.8853900817779268f
#define INV_SQRT_H 0.03608439182435161f

__device__ __forceinline__ float exp2_hw(float x) { return __builtin_amdgcn_exp2f(x); }
__device__ __forceinline__ float rcp_hw(float x) { return __builtin_amdgcn_rcpf(x); }

// ---------------- K1: att[i][j] = sum_k tanh(x_i[k]*y_j[k]) / sqrt(H) ----------------
// 8x8 tile per block; both 8x768 fp32 tiles staged in LDS (48KB -> 3 blocks/CU).
// wave-per-(i,j) pair, lanes over k, float4 LDS reads (conflict-free).
// tanh(z) = 1 - 2/(e^{2z}+1); y staged pre-scaled by 2*log2(e) so e^{2z} = exp2(x*ys).
__global__ __launch_bounds__(256) void k_att(const float* __restrict__ X,
                                             const float* __restrict__ Y,
                                             float* __restrict__ att) {
    __shared__ float xs[8 * HH];
    __shared__ float ys[8 * HH];
    const int tid = threadIdx.x;
    const int i0 = blockIdx.y * 8, j0 = blockIdx.x * 8;

    const float4* gx = (const float4*)(X + i0 * HH);
    const float4* gy = (const float4*)(Y + j0 * HH);
    float4* xs4 = (float4*)xs;
    float4* ys4 = (float4*)ys;
#pragma unroll
    for (int p = 0; p < 6; p++) {
        int e = tid + p * 256;
        float4 vx = gx[e];
        float4 vy = gy[e];
        xs4[e] = vx;
        vy.x *= TWO_L2E; vy.y *= TWO_L2E; vy.z *= TWO_L2E; vy.w *= TWO_L2E;
        ys4[e] = vy;
    }
    __syncthreads();

    const int wv = tid >> 6, ln = tid & 63;
    for (int q = 0; q < 16; q++) {
        int p = wv * 16 + q;
        const float4* xr = (const float4*)(xs + (p >> 3) * HH);
        const float4* yr = (const float4*)(ys + (p & 7) * HH);
        float acc = 0.f;
#pragma unroll
        for (int m = 0; m < 3; m++) {
            float4 a = xr[m * 64 + ln];
            float4 b = yr[m * 64 + ln];
            acc += rcp_hw(exp2_hw(a.x * b.x) + 1.f);
            acc += rcp_hw(exp2_hw(a.y * b.y) + 1.f);
            acc += rcp_hw(exp2_hw(a.z * b.z) + 1.f);
            acc += rcp_hw(exp2_hw(a.w * b.w) + 1.f);
        }
#pragma unroll
        for (int o = 32; o; o >>= 1) acc += __shfl_xor(acc, o, 64);
        if (ln == 0) {
            att[(i0 + (p >> 3)) * NN + (j0 + (p & 7))] = (768.f - 2.f * acc) * INV_SQRT_H;
        }
    }
}

// ---------------- K2: per-row / per-col max and reciprocal expsum ----------------
// blocks 0..383: row stats; 384..767: col stats. Softmax via exp2((a-M)*L2E).
__global__ __launch_bounds__(256) void k_stats(const float* __restrict__ att, float* rowM,
                                               float* rowRS, float* colM, float* colRS) {
    __shared__ float red[4];
    int b = blockIdx.x, t = threadIdx.x;
    bool isRow = b < NN;
    int x = isRow ? b : b - NN;
    float a0 = isRow ? att[x * NN + t] : att[t * NN + x];
    float a1 = (t < 128) ? (isRow ? att[x * NN + t + 256] : att[(t + 256) * NN + x]) : -1e30f;
    float m = fmaxf(a0, a1);
#pragma unroll
    for (int o = 32; o; o >>= 1) m = fmaxf(m, __shfl_xor(m, o, 64));
    if ((t & 63) == 0) red[t >> 6] = m;
    __syncthreads();
    float M = fmaxf(fmaxf(red[0], red[1]), fmaxf(red[2], red[3]));
    __syncthreads();
    float s = exp2_hw((a0 - M) * L2E);
    if (t < 128) s += exp2_hw((a1 - M) * L2E);
#pragma unroll
    for (int o = 32; o; o >>= 1) s += __shfl_xor(s, o, 64);
    if ((t & 63) == 0) red[t >> 6] = s;
    __syncthreads();
    if (t == 0) {
        float S = (red[0] + red[1]) + (red[2] + red[3]);
        if (isRow) { rowM[x] = M; rowRS[x] = 1.f / S; }
        else       { colM[x] = M; colRS[x] = 1.f / S; }
    }
}

// ---------------- K3: typicalness vectors ----------------
// hyper_typ[j] = (1/384) * sum_i Prow[i][j] ; hypo_typ[i] = (1/384) * sum_j Pcol[i][j]
__global__ __launch_bounds__(256) void k_typ(const float* __restrict__ att,
                                             const float* __restrict__ rowM,
                                             const float* __restrict__ rowRS,
                                             const float* __restrict__ colM,
                                             const float* __restrict__ colRS,
                                             float* hyper_typ, float* hypo_typ) {
    __shared__ float red[4];
    int b = blockIdx.x, t = threadIdx.x;
    bool isCol = b < NN;
    int x = isCol ? b : b - NN;
    float s = 0.f;
    if (isCol) {
        int j = x;
        for (int i = t; i < NN; i += 256)
            s += exp2_hw((att[i * NN + j] - rowM[i]) * L2E) * rowRS[i];
    } else {
        int i = x;
        for (int j = t; j < NN; j += 256)
            s += exp2_hw((att[i * NN + j] - colM[j]) * L2E) * colRS[j];
    }
#pragma unroll
    for (int o = 32; o; o >>= 1) s += __shfl_xor(s, o, 64);
    if ((t & 63) == 0) red[t >> 6] = s;
    __syncthreads();
    if (t == 0) {
        float S = (red[0] + red[1]) + (red[2] + red[3]);
        if (isCol) hyper_typ[x] = S * (1.f / NN);
        else       hypo_typ[x]  = S * (1.f / NN);
    }
}

// ---------------- K4: attention weight vectors ----------------
// w_hyper[j] = sum_i Prow[i][j]*hypo_typ[i] ; w_hypo[i] = sum_j Pcol[i][j]*hyper_typ[j]
__global__ __launch_bounds__(256) void k_w(const float* __restrict__ att,
                                           const float* __restrict__ rowM,
                                           const float* __restrict__ rowRS,
                                           const float* __restrict__ colM,
                                           const float* __restrict__ colRS,
                                           const float* __restrict__ hypo_typ,
                                           const float* __restrict__ hyper_typ,
                                           float* w_hyper, float* w_hypo) {
    __shared__ float red[4];
    int b = blockIdx.x, t = threadIdx.x;
    bool isCol = b < NN;
    int x = isCol ? b : b - NN;
    float s = 0.f;
    if (isCol) {
        int j = x;
        for (int i = t; i < NN; i += 256)
            s += exp2_hw((att[i * NN + j] - rowM[i]) * L2E) * rowRS[i] * hypo_typ[i];
    } else {
        int i = x;
        for (int j = t; j < NN; j += 256)
            s += exp2_hw((att[i * NN + j] - colM[j]) * L2E) * colRS[j] * hyper_typ[j];
    }
#pragma unroll
    for (int o = 32; o; o >>= 1) s += __shfl_xor(s, o, 64);
    if ((t & 63) == 0) red[t >> 6] = s;
    __syncthreads();
    if (t == 0) {
        float S = (red[0] + red[1]) + (red[2] + red[3]);
        if (isCol) w_hyper[x] = S;
        else       w_hypo[x]  = S;
    }
}

// ---------------- K5: prototypes ----------------
// hp[d] = sum_j w_hyper[j]*Y[j][d] ; hq[d] = sum_i w_hypo[i]*X[i][d]
__global__ __launch_bounds__(256) void k_proto(const float* __restrict__ X,
                                               const float* __restrict__ Y,
                                               const float* __restrict__ w_hyper,
                                               const float* __restrict__ w_hypo,
                                               float* hp, float* hq) {
    __shared__ float red[4][64];
    int b = blockIdx.x, t = threadIdx.x;
    bool hyper = b < 12;
    int bb = hyper ? b : b - 12;
    int dl = t & 63, w = t >> 6;
    int d = bb * 64 + dl;
    float s = 0.f;
    if (hyper) {
        for (int j = w * 96; j < w * 96 + 96; j++) s += w_hyper[j] * Y[j * HH + d];
    } else {
        for (int i = w * 96; i < w * 96 + 96; i++) s += w_hypo[i] * X[i * HH + d];
    }
    red[w][dl] = s;
    __syncthreads();
    if (t < 64) {
        float S = red[0][t] + red[1][t] + red[2][t] + red[3][t];
        if (hyper) hp[bb * 64 + t] = S;
        else       hq[bb * 64 + t] = S;
    }
}

// ---------------- K6: feats + classifier (fp32 output) ----------------
__global__ __launch_bounds__(256) void k_cls(const float* __restrict__ W,
                                             const float* __restrict__ bias,
                                             const float* __restrict__ hp,
                                             const float* __restrict__ hq,
                                             float* __restrict__ out) {
    __shared__ float red[3][4];
    int t = threadIdx.x;
    float acc0 = 0.f, acc1 = 0.f, acc2 = 0.f;
    for (int d = t; d < 4 * HH; d += 256) {
        int seg = d / HH, r = d - seg * HH;
        float f = (seg == 0) ? hp[r] : (seg == 1) ? hq[r] : (seg == 2) ? (hp[r] - hq[r]) : (hp[r] * hq[r]);
        acc0 += W[d] * f;
        acc1 += W[3072 + d] * f;
        acc2 += W[6144 + d] * f;
    }
#pragma unroll
    for (int o = 32; o; o >>= 1) {
        acc0 += __shfl_xor(acc0, o, 64);
        acc1 += __shfl_xor(acc1, o, 64);
        acc2 += __shfl_xor(acc2, o, 64);
    }
    if ((t & 63) == 0) {
        red[0][t >> 6] = acc0;
        red[1][t >> 6] = acc1;
        red[2][t >> 6] = acc2;
    }
    __syncthreads();
    if (t < 3) {
        float S = red[t][0] + red[t][1] + red[t][2] + red[t][3] + bias[t];
        out[t] = S;
    }
}

extern "C" void kernel_launch(void* const* d_in, const int* in_sizes, int n_in,
                              void* d_out, int out_size, void* d_ws, size_t ws_size,
                              hipStream_t stream) {
    const float* X = (const float*)d_in[0];   // hypo_embeddings [384,768] fp32
    const float* Y = (const float*)d_in[1];   // hyper_embeddings [384,768] fp32
    const float* W = (const float*)d_in[2];   // W_cls [3,3072] fp32
    const float* B = (const float*)d_in[3];   // b_cls [3] fp32
    float* out = (float*)d_out;               // fp32 output (reference returns float32)

    float* ws = (float*)d_ws;
    float* att       = ws;                 // 147456
    float* rowM      = att + NN * NN;      // 384
    float* rowRS     = rowM + NN;
    float* colM      = rowRS + NN;
    float* colRS     = colM + NN;
    float* hyper_typ = colRS + NN;
    float* hypo_typ  = hyper_typ + NN;
    float* w_hyper   = hypo_typ + NN;
    float* w_hypo    = w_hyper + NN;
    float* hp        = w_hypo + NN;        // 768
    float* hq        = hp + HH;            // 768

    k_att<<<dim3(48, 48), 256, 0, stream>>>(X, Y, att);
    k_stats<<<768, 256, 0, stream>>>(att, rowM, rowRS, colM, colRS);
    k_typ<<<768, 256, 0, stream>>>(att, rowM, rowRS, colM, colRS, hyper_typ, hypo_typ);
    k_w<<<768, 256, 0, stream>>>(att, rowM, rowRS, colM, colRS, hypo_typ, hyper_typ, w_hyper, w_hypo);
    k_proto<<<24, 256, 0, stream>>>(X, Y, w_hyper, w_hypo, hp, hq);
    k_cls<<<1, 256, 0, stream>>>(W, B, hp, hq, out);
}

// Round 5
// 107.886 us; speedup vs baseline: 1.0502x; 1.0502x over previous
//
#include <hip/hip_runtime.h>
#include <hip/hip_bf16.h>

#define NN 384
#define HH 768
#define L2E 1.4426950408889634f
#define TWO_L2E 2.8853900817779268f
#define INV_SQRT_H 0.03608439182435161f

__device__ __forceinline__ float exp2_hw(float x) { return __builtin_amdgcn_exp2f(x); }
__device__ __forceinline__ float rcp_hw(float x) { return __builtin_amdgcn_rcpf(x); }

// ---------------- K1: att[i][j] = sum_k tanh(x_i[k]*y_j[k]) / sqrt(H) ----------------
// 8x8 tile per block; both 8x768 fp32 tiles staged in LDS (48KB -> 3 blocks/CU).
// 512 threads = 8 waves/block -> 24 resident waves/CU (6/SIMD) to hide trans-op
// and LDS latency (was 4 waves/block -> 3/SIMD -> VALUBusy 58%).
// Each wave computes 8 of the 64 outputs: lanes over k, float4 LDS reads.
// tanh(z) = 1 - 2/(e^{2z}+1); y staged pre-scaled by 2*log2(e) so e^{2z} = exp2(x*ys).
__global__ __launch_bounds__(512) void k_att(const float* __restrict__ X,
                                             const float* __restrict__ Y,
                                             float* __restrict__ att) {
    __shared__ float xs[8 * HH];
    __shared__ float ys[8 * HH];
    const int tid = threadIdx.x;
    const int i0 = blockIdx.y * 8, j0 = blockIdx.x * 8;

    // stage: 8 rows x 768 fp32 = 1536 float4 per matrix; 512 threads -> 3 each
    const float4* gx = (const float4*)(X + i0 * HH);
    const float4* gy = (const float4*)(Y + j0 * HH);
    float4* xs4 = (float4*)xs;
    float4* ys4 = (float4*)ys;
#pragma unroll
    for (int p = 0; p < 3; p++) {
        int e = tid + p * 512;
        float4 vx = gx[e];
        float4 vy = gy[e];
        xs4[e] = vx;
        vy.x *= TWO_L2E; vy.y *= TWO_L2E; vy.z *= TWO_L2E; vy.w *= TWO_L2E;
        ys4[e] = vy;
    }
    __syncthreads();

    const int wv = tid >> 6, ln = tid & 63;
#pragma unroll
    for (int q = 0; q < 8; q++) {
        int p = wv * 8 + q;
        const float4* xr = (const float4*)(xs + (p >> 3) * HH);
        const float4* yr = (const float4*)(ys + (p & 7) * HH);
        float acc = 0.f;
#pragma unroll
        for (int m = 0; m < 3; m++) {
            float4 a = xr[m * 64 + ln];
            float4 b = yr[m * 64 + ln];
            acc += rcp_hw(exp2_hw(a.x * b.x) + 1.f);
            acc += rcp_hw(exp2_hw(a.y * b.y) + 1.f);
            acc += rcp_hw(exp2_hw(a.z * b.z) + 1.f);
            acc += rcp_hw(exp2_hw(a.w * b.w) + 1.f);
        }
#pragma unroll
        for (int o = 32; o; o >>= 1) acc += __shfl_xor(acc, o, 64);
        if (ln == 0) {
            att[(i0 + (p >> 3)) * NN + (j0 + (p & 7))] = (768.f - 2.f * acc) * INV_SQRT_H;
        }
    }
}

// ---------------- K2: per-row / per-col max and reciprocal expsum ----------------
// blocks 0..383: row stats; 384..767: col stats. Softmax via exp2((a-M)*L2E).
__global__ __launch_bounds__(256) void k_stats(const float* __restrict__ att, float* rowM,
                                               float* rowRS, float* colM, float* colRS) {
    __shared__ float red[4];
    int b = blockIdx.x, t = threadIdx.x;
    bool isRow = b < NN;
    int x = isRow ? b : b - NN;
    float a0 = isRow ? att[x * NN + t] : att[t * NN + x];
    float a1 = (t < 128) ? (isRow ? att[x * NN + t + 256] : att[(t + 256) * NN + x]) : -1e30f;
    float m = fmaxf(a0, a1);
#pragma unroll
    for (int o = 32; o; o >>= 1) m = fmaxf(m, __shfl_xor(m, o, 64));
    if ((t & 63) == 0) red[t >> 6] = m;
    __syncthreads();
    float M = fmaxf(fmaxf(red[0], red[1]), fmaxf(red[2], red[3]));
    __syncthreads();
    float s = exp2_hw((a0 - M) * L2E);
    if (t < 128) s += exp2_hw((a1 - M) * L2E);
#pragma unroll
    for (int o = 32; o; o >>= 1) s += __shfl_xor(s, o, 64);
    if ((t & 63) == 0) red[t >> 6] = s;
    __syncthreads();
    if (t == 0) {
        float S = (red[0] + red[1]) + (red[2] + red[3]);
        if (isRow) { rowM[x] = M; rowRS[x] = 1.f / S; }
        else       { colM[x] = M; colRS[x] = 1.f / S; }
    }
}

// ---------------- K3: typicalness vectors ----------------
// hyper_typ[j] = (1/384) * sum_i Prow[i][j] ; hypo_typ[i] = (1/384) * sum_j Pcol[i][j]
__global__ __launch_bounds__(256) void k_typ(const float* __restrict__ att,
                                             const float* __restrict__ rowM,
                                             const float* __restrict__ rowRS,
                                             const float* __restrict__ colM,
                                             const float* __restrict__ colRS,
                                             float* hyper_typ, float* hypo_typ) {
    __shared__ float red[4];
    int b = blockIdx.x, t = threadIdx.x;
    bool isCol = b < NN;
    int x = isCol ? b : b - NN;
    float s = 0.f;
    if (isCol) {
        int j = x;
        for (int i = t; i < NN; i += 256)
            s += exp2_hw((att[i * NN + j] - rowM[i]) * L2E) * rowRS[i];
    } else {
        int i = x;
        for (int j = t; j < NN; j += 256)
            s += exp2_hw((att[i * NN + j] - colM[j]) * L2E) * colRS[j];
    }
#pragma unroll
    for (int o = 32; o; o >>= 1) s += __shfl_xor(s, o, 64);
    if ((t & 63) == 0) red[t >> 6] = s;
    __syncthreads();
    if (t == 0) {
        float S = (red[0] + red[1]) + (red[2] + red[3]);
        if (isCol) hyper_typ[x] = S * (1.f / NN);
        else       hypo_typ[x]  = S * (1.f / NN);
    }
}

// ---------------- K4: attention weight vectors ----------------
// w_hyper[j] = sum_i Prow[i][j]*hypo_typ[i] ; w_hypo[i] = sum_j Pcol[i][j]*hyper_typ[j]
__global__ __launch_bounds__(256) void k_w(const float* __restrict__ att,
                                           const float* __restrict__ rowM,
                                           const float* __restrict__ rowRS,
                                           const float* __restrict__ colM,
                                           const float* __restrict__ colRS,
                                           const float* __restrict__ hypo_typ,
                                           const float* __restrict__ hyper_typ,
                                           float* w_hyper, float* w_hypo) {
    __shared__ float red[4];
    int b = blockIdx.x, t = threadIdx.x;
    bool isCol = b < NN;
    int x = isCol ? b : b - NN;
    float s = 0.f;
    if (isCol) {
        int j = x;
        for (int i = t; i < NN; i += 256)
            s += exp2_hw((att[i * NN + j] - rowM[i]) * L2E) * rowRS[i] * hypo_typ[i];
    } else {
        int i = x;
        for (int j = t; j < NN; j += 256)
            s += exp2_hw((att[i * NN + j] - colM[j]) * L2E) * colRS[j] * hyper_typ[j];
    }
#pragma unroll
    for (int o = 32; o; o >>= 1) s += __shfl_xor(s, o, 64);
    if ((t & 63) == 0) red[t >> 6] = s;
    __syncthreads();
    if (t == 0) {
        float S = (red[0] + red[1]) + (red[2] + red[3]);
        if (isCol) w_hyper[x] = S;
        else       w_hypo[x]  = S;
    }
}

// ---------------- K5: prototypes ----------------
// hp[d] = sum_j w_hyper[j]*Y[j][d] ; hq[d] = sum_i w_hypo[i]*X[i][d]
__global__ __launch_bounds__(256) void k_proto(const float* __restrict__ X,
                                               const float* __restrict__ Y,
                                               const float* __restrict__ w_hyper,
                                               const float* __restrict__ w_hypo,
                                               float* hp, float* hq) {
    __shared__ float red[4][64];
    int b = blockIdx.x, t = threadIdx.x;
    bool hyper = b < 12;
    int bb = hyper ? b : b - 12;
    int dl = t & 63, w = t >> 6;
    int d = bb * 64 + dl;
    float s = 0.f;
    if (hyper) {
        for (int j = w * 96; j < w * 96 + 96; j++) s += w_hyper[j] * Y[j * HH + d];
    } else {
        for (int i = w * 96; i < w * 96 + 96; i++) s += w_hypo[i] * X[i * HH + d];
    }
    red[w][dl] = s;
    __syncthreads();
    if (t < 64) {
        float S = red[0][t] + red[1][t] + red[2][t] + red[3][t];
        if (hyper) hp[bb * 64 + t] = S;
        else       hq[bb * 64 + t] = S;
    }
}

// ---------------- K6: feats + classifier (fp32 output) ----------------
__global__ __launch_bounds__(256) void k_cls(const float* __restrict__ W,
                                             const float* __restrict__ bias,
                                             const float* __restrict__ hp,
                                             const float* __restrict__ hq,
                                             float* __restrict__ out) {
    __shared__ float red[3][4];
    int t = threadIdx.x;
    float acc0 = 0.f, acc1 = 0.f, acc2 = 0.f;
    for (int d = t; d < 4 * HH; d += 256) {
        int seg = d / HH, r = d - seg * HH;
        float f = (seg == 0) ? hp[r] : (seg == 1) ? hq[r] : (seg == 2) ? (hp[r] - hq[r]) : (hp[r] * hq[r]);
        acc0 += W[d] * f;
        acc1 += W[3072 + d] * f;
        acc2 += W[6144 + d] * f;
    }
#pragma unroll
    for (int o = 32; o; o >>= 1) {
        acc0 += __shfl_xor(acc0, o, 64);
        acc1 += __shfl_xor(acc1, o, 64);
        acc2 += __shfl_xor(acc2, o, 64);
    }
    if ((t & 63) == 0) {
        red[0][t >> 6] = acc0;
        red[1][t >> 6] = acc1;
        red[2][t >> 6] = acc2;
    }
    __syncthreads();
    if (t < 3) {
        float S = red[t][0] + red[t][1] + red[t][2] + red[t][3] + bias[t];
        out[t] = S;
    }
}

extern "C" void kernel_launch(void* const* d_in, const int* in_sizes, int n_in,
                              void* d_out, int out_size, void* d_ws, size_t ws_size,
                              hipStream_t stream) {
    const float* X = (const float*)d_in[0];   // hypo_embeddings [384,768] fp32
    const float* Y = (const float*)d_in[1];   // hyper_embeddings [384,768] fp32
    const float* W = (const float*)d_in[2];   // W_cls [3,3072] fp32
    const float* B = (const float*)d_in[3];   // b_cls [3] fp32
    float* out = (float*)d_out;               // fp32 output

    float* ws = (float*)d_ws;
    float* att       = ws;                 // 147456
    float* rowM      = att + NN * NN;      // 384
    float* rowRS     = rowM + NN;
    float* colM      = rowRS + NN;
    float* colRS     = colM + NN;
    float* hyper_typ = colRS + NN;
    float* hypo_typ  = hyper_typ + NN;
    float* w_hyper   = hypo_typ + NN;
    float* w_hypo    = w_hyper + NN;
    float* hp        = w_hypo + NN;        // 768
    float* hq        = hp + HH;            // 768

    k_att<<<dim3(48, 48), 512, 0, stream>>>(X, Y, att);
    k_stats<<<768, 256, 0, stream>>>(att, rowM, rowRS, colM, colRS);
    k_typ<<<768, 256, 0, stream>>>(att, rowM, rowRS, colM, colRS, hyper_typ, hypo_typ);
    k_w<<<768, 256, 0, stream>>>(att, rowM, rowRS, colM, colRS, hypo_typ, hyper_typ, w_hyper, w_hypo);
    k_proto<<<24, 256, 0, stream>>>(X, Y, w_hyper, w_hypo, hp, hq);
    k_cls<<<1, 256, 0, stream>>>(W, B, hp, hq, out);
}

// Round 6
// 103.219 us; speedup vs baseline: 1.0977x; 1.0452x over previous
//
#include <hip/hip_runtime.h>
#include <hip/hip_bf16.h>

#define NN 384
#define HH 768
#define HP 772   // padded LDS row (772%8==4 -> row bases spread over banks, 16B aligned)
#define L2E 1.4426950408889634f
#define TWO_L2E 2.8853900817779268f
#define INV_SQRT_H 0.03608439182435161f

__device__ __forceinline__ float exp2_hw(float x) { return __builtin_amdgcn_exp2f(x); }
__device__ __forceinline__ float rcp_hw(float x) { return __builtin_amdgcn_rcpf(x); }

// ---------------- K1: att[i][j] = sum_k tanh(x_i[k]*y_j[k]) / sqrt(H) ----------------
// Lane-per-output: lane (i,j) of each wave accumulates its own dot privately in 4
// independent chains (float4), NO cross-lane shuffles in the hot loop. 4 waves split
// k 4-ways (192 each); one tiny LDS reduction at the end. LDS rows padded to 772
// floats: 8 row bases hit bank-quads 0,4,...,28 -> 8-lane broadcast per address,
// conflict-free ds_read_b128. tanh(z) = 1 - 2/(e^{2z}+1); y pre-scaled by 2*log2(e).
__global__ __launch_bounds__(256) void k_att(const float* __restrict__ X,
                                             const float* __restrict__ Y,
                                             float* __restrict__ att) {
    __shared__ float xs[8 * HP];
    __shared__ float ys[8 * HP];
    __shared__ float part[4][64];
    const int tid = threadIdx.x;
    const int i0 = blockIdx.y * 8, j0 = blockIdx.x * 8;

    // stage: 8 rows x 192 float4 per matrix (1536 float4), written into padded rows
    const float4* gx = (const float4*)(X + i0 * HH);
    const float4* gy = (const float4*)(Y + j0 * HH);
#pragma unroll
    for (int p = 0; p < 6; p++) {
        int e = tid + p * 256;
        int r = e / 192, c = e - r * 192;
        float4 vx = gx[e];
        float4 vy = gy[e];
        ((float4*)(xs + r * HP))[c] = vx;
        vy.x *= TWO_L2E; vy.y *= TWO_L2E; vy.z *= TWO_L2E; vy.w *= TWO_L2E;
        ((float4*)(ys + r * HP))[c] = vy;
    }
    __syncthreads();

    const int wv = tid >> 6, ln = tid & 63;
    const int i = ln >> 3, j = ln & 7;
    const float4* xr = (const float4*)(xs + i * HP) + wv * 48;
    const float4* yr = (const float4*)(ys + j * HP) + wv * 48;
    float a0 = 0.f, a1 = 0.f, a2 = 0.f, a3 = 0.f;
#pragma unroll 8
    for (int m = 0; m < 48; m++) {
        float4 a = xr[m];
        float4 b = yr[m];
        a0 += rcp_hw(exp2_hw(a.x * b.x) + 1.f);
        a1 += rcp_hw(exp2_hw(a.y * b.y) + 1.f);
        a2 += rcp_hw(exp2_hw(a.z * b.z) + 1.f);
        a3 += rcp_hw(exp2_hw(a.w * b.w) + 1.f);
    }
    part[wv][ln] = (a0 + a1) + (a2 + a3);
    __syncthreads();
    if (tid < 64) {
        float s = part[0][tid] + part[1][tid] + part[2][tid] + part[3][tid];
        int ii = tid >> 3, jj = tid & 7;
        att[(i0 + ii) * NN + (j0 + jj)] = (768.f - 2.f * s) * INV_SQRT_H;
    }
}

// ---------------- K2: per-row / per-col max and reciprocal expsum ----------------
// blocks 0..383: row stats; 384..767: col stats. Softmax via exp2((a-M)*L2E).
__global__ __launch_bounds__(256) void k_stats(const float* __restrict__ att, float* rowM,
                                               float* rowRS, float* colM, float* colRS) {
    __shared__ float red[4];
    int b = blockIdx.x, t = threadIdx.x;
    bool isRow = b < NN;
    int x = isRow ? b : b - NN;
    float a0 = isRow ? att[x * NN + t] : att[t * NN + x];
    float a1 = (t < 128) ? (isRow ? att[x * NN + t + 256] : att[(t + 256) * NN + x]) : -1e30f;
    float m = fmaxf(a0, a1);
#pragma unroll
    for (int o = 32; o; o >>= 1) m = fmaxf(m, __shfl_xor(m, o, 64));
    if ((t & 63) == 0) red[t >> 6] = m;
    __syncthreads();
    float M = fmaxf(fmaxf(red[0], red[1]), fmaxf(red[2], red[3]));
    __syncthreads();
    float s = exp2_hw((a0 - M) * L2E);
    if (t < 128) s += exp2_hw((a1 - M) * L2E);
#pragma unroll
    for (int o = 32; o; o >>= 1) s += __shfl_xor(s, o, 64);
    if ((t & 63) == 0) red[t >> 6] = s;
    __syncthreads();
    if (t == 0) {
        float S = (red[0] + red[1]) + (red[2] + red[3]);
        if (isRow) { rowM[x] = M; rowRS[x] = 1.f / S; }
        else       { colM[x] = M; colRS[x] = 1.f / S; }
    }
}

// ---------------- K3: typicalness vectors ----------------
// hyper_typ[j] = (1/384) * sum_i Prow[i][j] ; hypo_typ[i] = (1/384) * sum_j Pcol[i][j]
__global__ __launch_bounds__(256) void k_typ(const float* __restrict__ att,
                                             const float* __restrict__ rowM,
                                             const float* __restrict__ rowRS,
                                             const float* __restrict__ colM,
                                             const float* __restrict__ colRS,
                                             float* hyper_typ, float* hypo_typ) {
    __shared__ float red[4];
    int b = blockIdx.x, t = threadIdx.x;
    bool isCol = b < NN;
    int x = isCol ? b : b - NN;
    float s = 0.f;
    if (isCol) {
        int j = x;
        for (int i = t; i < NN; i += 256)
            s += exp2_hw((att[i * NN + j] - rowM[i]) * L2E) * rowRS[i];
    } else {
        int i = x;
        for (int j = t; j < NN; j += 256)
            s += exp2_hw((att[i * NN + j] - colM[j]) * L2E) * colRS[j];
    }
#pragma unroll
    for (int o = 32; o; o >>= 1) s += __shfl_xor(s, o, 64);
    if ((t & 63) == 0) red[t >> 6] = s;
    __syncthreads();
    if (t == 0) {
        float S = (red[0] + red[1]) + (red[2] + red[3]);
        if (isCol) hyper_typ[x] = S * (1.f / NN);
        else       hypo_typ[x]  = S * (1.f / NN);
    }
}

// ---------------- K4: attention weight vectors ----------------
// w_hyper[j] = sum_i Prow[i][j]*hypo_typ[i] ; w_hypo[i] = sum_j Pcol[i][j]*hyper_typ[j]
__global__ __launch_bounds__(256) void k_w(const float* __restrict__ att,
                                           const float* __restrict__ rowM,
                                           const float* __restrict__ rowRS,
                                           const float* __restrict__ colM,
                                           const float* __restrict__ colRS,
                                           const float* __restrict__ hypo_typ,
                                           const float* __restrict__ hyper_typ,
                                           float* w_hyper, float* w_hypo) {
    __shared__ float red[4];
    int b = blockIdx.x, t = threadIdx.x;
    bool isCol = b < NN;
    int x = isCol ? b : b - NN;
    float s = 0.f;
    if (isCol) {
        int j = x;
        for (int i = t; i < NN; i += 256)
            s += exp2_hw((att[i * NN + j] - rowM[i]) * L2E) * rowRS[i] * hypo_typ[i];
    } else {
        int i = x;
        for (int j = t; j < NN; j += 256)
            s += exp2_hw((att[i * NN + j] - colM[j]) * L2E) * colRS[j] * hyper_typ[j];
    }
#pragma unroll
    for (int o = 32; o; o >>= 1) s += __shfl_xor(s, o, 64);
    if ((t & 63) == 0) red[t >> 6] = s;
    __syncthreads();
    if (t == 0) {
        float S = (red[0] + red[1]) + (red[2] + red[3]);
        if (isCol) w_hyper[x] = S;
        else       w_hypo[x]  = S;
    }
}

// ---------------- K5: prototypes ----------------
// hp[d] = sum_j w_hyper[j]*Y[j][d] ; hq[d] = sum_i w_hypo[i]*X[i][d]
__global__ __launch_bounds__(256) void k_proto(const float* __restrict__ X,
                                               const float* __restrict__ Y,
                                               const float* __restrict__ w_hyper,
                                               const float* __restrict__ w_hypo,
                                               float* hp, float* hq) {
    __shared__ float red[4][64];
    int b = blockIdx.x, t = threadIdx.x;
    bool hyper = b < 12;
    int bb = hyper ? b : b - 12;
    int dl = t & 63, w = t >> 6;
    int d = bb * 64 + dl;
    float s = 0.f;
    if (hyper) {
        for (int j = w * 96; j < w * 96 + 96; j++) s += w_hyper[j] * Y[j * HH + d];
    } else {
        for (int i = w * 96; i < w * 96 + 96; i++) s += w_hypo[i] * X[i * HH + d];
    }
    red[w][dl] = s;
    __syncthreads();
    if (t < 64) {
        float S = red[0][t] + red[1][t] + red[2][t] + red[3][t];
        if (hyper) hp[bb * 64 + t] = S;
        else       hq[bb * 64 + t] = S;
    }
}

// ---------------- K6: feats + classifier (fp32 output) ----------------
__global__ __launch_bounds__(256) void k_cls(const float* __restrict__ W,
                                             const float* __restrict__ bias,
                                             const float* __restrict__ hp,
                                             const float* __restrict__ hq,
                                             float* __restrict__ out) {
    __shared__ float red[3][4];
    int t = threadIdx.x;
    float acc0 = 0.f, acc1 = 0.f, acc2 = 0.f;
    for (int d = t; d < 4 * HH; d += 256) {
        int seg = d / HH, r = d - seg * HH;
        float f = (seg == 0) ? hp[r] : (seg == 1) ? hq[r] : (seg == 2) ? (hp[r] - hq[r]) : (hp[r] * hq[r]);
        acc0 += W[d] * f;
        acc1 += W[3072 + d] * f;
        acc2 += W[6144 + d] * f;
    }
#pragma unroll
    for (int o = 32; o; o >>= 1) {
        acc0 += __shfl_xor(acc0, o, 64);
        acc1 += __shfl_xor(acc1, o, 64);
        acc2 += __shfl_xor(acc2, o, 64);
    }
    if ((t & 63) == 0) {
        red[0][t >> 6] = acc0;
        red[1][t >> 6] = acc1;
        red[2][t >> 6] = acc2;
    }
    __syncthreads();
    if (t < 3) {
        float S = red[t][0] + red[t][1] + red[t][2] + red[t][3] + bias[t];
        out[t] = S;
    }
}

extern "C" void kernel_launch(void* const* d_in, const int* in_sizes, int n_in,
                              void* d_out, int out_size, void* d_ws, size_t ws_size,
                              hipStream_t stream) {
    const float* X = (const float*)d_in[0];   // hypo_embeddings [384,768] fp32
    const float* Y = (const float*)d_in[1];   // hyper_embeddings [384,768] fp32
    const float* W = (const float*)d_in[2];   // W_cls [3,3072] fp32
    const float* B = (const float*)d_in[3];   // b_cls [3] fp32
    float* out = (float*)d_out;               // fp32 output

    float* ws = (float*)d_ws;
    float* att       = ws;                 // 147456
    float* rowM      = att + NN * NN;      // 384
    float* rowRS     = rowM + NN;
    float* colM      = rowRS + NN;
    float* colRS     = colM + NN;
    float* hyper_typ = colRS + NN;
    float* hypo_typ  = hyper_typ + NN;
    float* w_hyper   = hypo_typ + NN;
    float* w_hypo    = w_hyper + NN;
    float* hp        = w_hypo + NN;        // 768
    float* hq        = hp + HH;            // 768

    k_att<<<dim3(48, 48), 256, 0, stream>>>(X, Y, att);
    k_stats<<<768, 256, 0, stream>>>(att, rowM, rowRS, colM, colRS);
    k_typ<<<768, 256, 0, stream>>>(att, rowM, rowRS, colM, colRS, hyper_typ, hypo_typ);
    k_w<<<768, 256, 0, stream>>>(att, rowM, rowRS, colM, colRS, hypo_typ, hyper_typ, w_hyper, w_hypo);
    k_proto<<<24, 256, 0, stream>>>(X, Y, w_hyper, w_hypo, hp, hq);
    k_cls<<<1, 256, 0, stream>>>(W, B, hp, hq, out);
}